// Round 2
// baseline (316.673 us; speedup 1.0000x reference)
//
#include <hip/hip_runtime.h>
#include <hip/hip_bf16.h>

// y[b, c] = (sum_k x[b,k] * W[c % 512, k]) + bias[c]
// Split-K=4 bf16-MFMA GEMM (partials land in column-copies 0..3 of d_out),
// then a streaming combine: sum 4 partials + bias -> all 8 column copies.
// GEMM K-loop: LDS double-buffer (1 barrier/iter) + register prefetch depth 2.

typedef __bf16 bf8 __attribute__((ext_vector_type(8)));
typedef float f4 __attribute__((ext_vector_type(4)));
typedef unsigned int uint;

constexpr int M = 4096;
constexpr int K = 4096;
constexpr int NS = 512;          // shared rows = y_small columns
constexpr int OUTF = 4096;       // output columns
constexpr int BM = 128, BN = 128, BK = 32;
constexpr int SK = 4;            // K splits -> partials in d_out copies 0..3
constexpr int KS = K / SK;       // 1024 per split
constexpr int NITER = KS / BK;   // 32 K-iterations per block
constexpr int BKP = BK + 8;      // padded LDS stride (80 B, 16B-aligned)

#define PERM_HI2(hi, lo) __builtin_amdgcn_perm((hi), (lo), 0x07060302u)

__device__ __forceinline__ void pack_tile(const float4 g[4], uint4& p0, uint4& p1) {
  uint4 u0 = __builtin_bit_cast(uint4, g[0]);
  uint4 u1 = __builtin_bit_cast(uint4, g[1]);
  uint4 u2 = __builtin_bit_cast(uint4, g[2]);
  uint4 u3 = __builtin_bit_cast(uint4, g[3]);
  p0.x = PERM_HI2(u0.y, u0.x); p0.y = PERM_HI2(u0.w, u0.z);
  p0.z = PERM_HI2(u1.y, u1.x); p0.w = PERM_HI2(u1.w, u1.z);
  p1.x = PERM_HI2(u2.y, u2.x); p1.y = PERM_HI2(u2.w, u2.z);
  p1.z = PERM_HI2(u3.y, u3.x); p1.w = PERM_HI2(u3.w, u3.z);
}

__global__ __launch_bounds__(256, 2)
void gemm_split_kernel(const float* __restrict__ x, const float* __restrict__ w,
                       float* __restrict__ out) {
  __shared__ __align__(16) unsigned short As[2][BM * BKP];
  __shared__ __align__(16) unsigned short Bs[2][BN * BKP];

  const int gid = blockIdx.x;          // 512 blocks
  const int mt = gid & 31;             // 32 M tiles
  const int nt = (gid >> 5) & 3;       // 4 N tiles
  const int s  = gid >> 7;             // 4 K splits

  const int tid = threadIdx.x;
  const int row2 = tid >> 1;           // 0..127: staging row
  const int kc   = (tid & 1) << 4;     // 0 or 16: staging k-offset (16 floats)

  const float* xA = x + (size_t)(mt * BM + row2) * K + s * KS + kc;
  const float* wB = w + (size_t)(nt * BN + row2) * K + s * KS + kc;

  const int lane = tid & 63;
  const int wv = tid >> 6;
  const int wm = (wv & 1) * 64;        // wave M origin
  const int wn = (wv >> 1) * 64;       // wave N origin
  const int lr = lane & 15;
  const int lq = lane >> 4;

  f4 acc[4][4] = {};

  // two register slots of in-flight global tiles
  float4 ga[2][4], gb[2][4];
#pragma unroll
  for (int i = 0; i < 4; ++i) {
    ga[0][i] = *reinterpret_cast<const float4*>(xA + i * 4);
    gb[0][i] = *reinterpret_cast<const float4*>(wB + i * 4);
    ga[1][i] = *reinterpret_cast<const float4*>(xA + BK + i * 4);
    gb[1][i] = *reinterpret_cast<const float4*>(wB + BK + i * 4);
  }

  // pack tile 0 into LDS buffer 0
  {
    uint4 p0, p1;
    pack_tile(ga[0], p0, p1);
    *reinterpret_cast<uint4*>(&As[0][row2 * BKP + kc])     = p0;
    *reinterpret_cast<uint4*>(&As[0][row2 * BKP + kc + 8]) = p1;
    pack_tile(gb[0], p0, p1);
    *reinterpret_cast<uint4*>(&Bs[0][row2 * BKP + kc])     = p0;
    *reinterpret_cast<uint4*>(&Bs[0][row2 * BKP + kc + 8]) = p1;
  }
  __syncthreads();

  for (int kk = 0; kk < NITER; ++kk) {
    const int cur = kk & 1;
    const int nxt = cur ^ 1;

    // fragment loads from current LDS buffer
    bf8 af[4], bfv[4];
#pragma unroll
    for (int mf = 0; mf < 4; ++mf)
      af[mf] = *reinterpret_cast<const bf8*>(&As[cur][(wm + mf * 16 + lr) * BKP + lq * 8]);
#pragma unroll
    for (int nf = 0; nf < 4; ++nf)
      bfv[nf] = *reinterpret_cast<const bf8*>(&Bs[cur][(wn + nf * 16 + lr) * BKP + lq * 8]);

    // issue global loads for tile kk+2 into the just-freed register slot
    if (kk + 2 < NITER) {
      const float* xn = xA + (kk + 2) * BK;
      const float* wn2 = wB + (kk + 2) * BK;
#pragma unroll
      for (int i = 0; i < 4; ++i) {
        ga[cur][i] = *reinterpret_cast<const float4*>(xn + i * 4);
        gb[cur][i] = *reinterpret_cast<const float4*>(wn2 + i * 4);
      }
    }

    // MFMA on current tile
#pragma unroll
    for (int mf = 0; mf < 4; ++mf)
#pragma unroll
      for (int nf = 0; nf < 4; ++nf)
        acc[mf][nf] = __builtin_amdgcn_mfma_f32_16x16x32_bf16(af[mf], bfv[nf], acc[mf][nf], 0, 0, 0);

    // pack tile kk+1 (loaded >=1.5 iters ago) into the other LDS buffer
    if (kk + 1 < NITER) {
      uint4 p0, p1;
      pack_tile(ga[nxt], p0, p1);
      *reinterpret_cast<uint4*>(&As[nxt][row2 * BKP + kc])     = p0;
      *reinterpret_cast<uint4*>(&As[nxt][row2 * BKP + kc + 8]) = p1;
      pack_tile(gb[nxt], p0, p1);
      *reinterpret_cast<uint4*>(&Bs[nxt][row2 * BKP + kc])     = p0;
      *reinterpret_cast<uint4*>(&Bs[nxt][row2 * BKP + kc + 8]) = p1;
    }
    __syncthreads();
  }

  // epilogue: write fp32 partial into column-copy s of d_out
  float* ob = out + (size_t)(mt * BM) * OUTF + s * NS + nt * BN;
#pragma unroll
  for (int mf = 0; mf < 4; ++mf) {
#pragma unroll
    for (int nf = 0; nf < 4; ++nf) {
#pragma unroll
      for (int r = 0; r < 4; ++r) {
        const int row = wm + mf * 16 + lq * 4 + r;
        const int col = wn + nf * 16 + lr;
        ob[(size_t)row * OUTF + col] = acc[mf][nf][r];
      }
    }
  }
}

// Sum the 4 K-split partials (column copies 0..3), add bias, write all 8 copies.
__global__ __launch_bounds__(256)
void combine_kernel(float* __restrict__ out, const float* __restrict__ bias) {
  const int t = blockIdx.x * 256 + threadIdx.x;   // 524288 threads
  const int b  = t >> 7;                          // row 0..4095
  const int rc = t & 127;                         // float4 index within 512-col copy
  float4* row = reinterpret_cast<float4*>(out) + (size_t)b * (OUTF / 4);
  const float4* bias4 = reinterpret_cast<const float4*>(bias);

  float4 p[SK];
#pragma unroll
  for (int s2 = 0; s2 < SK; ++s2) p[s2] = row[s2 * 128 + rc];

  float sx = 0.f, sy = 0.f, sz = 0.f, sw = 0.f;
#pragma unroll
  for (int s2 = 0; s2 < SK; ++s2) {
    sx += p[s2].x; sy += p[s2].y; sz += p[s2].z; sw += p[s2].w;
  }

#pragma unroll
  for (int c = 0; c < 8; ++c) {
    float4 bb = bias4[c * 128 + rc];
    float4 o;
    o.x = sx + bb.x; o.y = sy + bb.y; o.z = sz + bb.z; o.w = sw + bb.w;
    row[c * 128 + rc] = o;
  }
}

extern "C" void kernel_launch(void* const* d_in, const int* in_sizes, int n_in,
                              void* d_out, int out_size, void* d_ws, size_t ws_size,
                              hipStream_t stream) {
  (void)in_sizes; (void)n_in; (void)d_ws; (void)ws_size; (void)out_size;
  const float* x    = (const float*)d_in[0];
  const float* w    = (const float*)d_in[1];
  const float* bias = (const float*)d_in[2];
  float* out = (float*)d_out;

  gemm_split_kernel<<<dim3(32 * 4 * SK), dim3(256), 0, stream>>>(x, w, out);
  combine_kernel<<<dim3((M * NS / 4) / 256), dim3(256), 0, stream>>>(out, bias);
}

// Round 3
// 167.784 us; speedup vs baseline: 1.8874x; 1.8874x over previous
//
#include <hip/hip_runtime.h>
#include <hip/hip_bf16.h>

// y[b, c] = (sum_k x[b,k] * W[c % 512, k]) + bias[c]
// Split-K=4 bf16-MFMA GEMM. fp32 tiles staged global->LDS via async
// global_load_lds DMA (no VGPR round-trip); fp32->bf16 conversion happens on
// the LDS->fragment path (ds_read_b128 x2 + v_perm x4 per fragment).
// Global-side chunk XOR-swizzle makes fragment reads bank-conflict-free
// despite global_load_lds's fixed linear LDS layout.
// Partials land in column-copies 0..3 of d_out; combine sums + bias -> 8 copies.

typedef __bf16 bf8 __attribute__((ext_vector_type(8)));
typedef float f4 __attribute__((ext_vector_type(4)));
typedef unsigned int uint;

constexpr int M = 4096;
constexpr int K = 4096;
constexpr int NS = 512;          // shared rows
constexpr int OUTF = 4096;       // output columns
constexpr int BM = 128, BN = 128, BK = 32;
constexpr int SK = 4;            // K splits -> partials in d_out copies 0..3
constexpr int KS = K / SK;       // 1024
constexpr int NITER = KS / BK;   // 32

#define PERM_HI2(hi, lo) __builtin_amdgcn_perm((hi), (lo), 0x07060302u)

__device__ __forceinline__ void async16(const float* g, float* l) {
  __builtin_amdgcn_global_load_lds(
      (const __attribute__((address_space(1))) void*)g,
      (__attribute__((address_space(3))) void*)l, 16, 0, 0);
}

// Convert one A/B fragment: 8 consecutive-k fp32 values living in LDS chunks
// q0 and q0^1 of this row -> 8 bf16.
__device__ __forceinline__ bf8 load_frag(const float* rowp, int q0) {
  const uint4* cp = reinterpret_cast<const uint4*>(rowp);
  uint4 lo = cp[q0];        // k elems 8lq..8lq+3 (fp32)
  uint4 hi = cp[q0 ^ 1];    // k elems 8lq+4..8lq+7
  uint4 f;
  f.x = PERM_HI2(lo.y, lo.x);
  f.y = PERM_HI2(lo.w, lo.z);
  f.z = PERM_HI2(hi.y, hi.x);
  f.w = PERM_HI2(hi.w, hi.z);
  return __builtin_bit_cast(bf8, f);
}

__global__ __launch_bounds__(256, 2)
void gemm_split_kernel(const float* __restrict__ x, const float* __restrict__ wgt,
                       float* __restrict__ out) {
  // raw fp32 tiles, double-buffered: 2 x (128x32x4B) per operand = 64 KB total
  __shared__ __align__(16) float As[2][BM * BK];
  __shared__ __align__(16) float Bs[2][BN * BK];

  const int gid = blockIdx.x;          // 512 blocks
  const int mt = gid & 31;             // 32 M tiles (fastest -> x-slab L2 share)
  const int nt = (gid >> 5) & 3;       // 4 N tiles
  const int s  = gid >> 7;             // 4 K splits

  const int tid  = threadIdx.x;
  const int wv   = tid >> 6;           // wave 0..3
  const int lane = tid & 63;

  // --- staging address precompute -------------------------------------
  // Tile = 128 rows x 32 fp32 = 1024 16B-chunks. LDS layout is linear in
  // chunk index c; we store global chunk j of row r at c = r*8 + (j ^ (r&7)).
  // Wave wv, call slot j covers chunks (wv*4+j)*64 + lane.
  int goff[4];
#pragma unroll
  for (int j = 0; j < 4; ++j) {
    const int c   = (wv * 4 + j) * 64 + lane;
    const int row = c >> 3;
    const int jg  = (c & 7) ^ (row & 7);   // swizzled global chunk within row
    goff[j] = row * K + jg * 4;            // float offset from tile base
  }
  const int lbase = wv * 1024;             // float offset of this wave's LDS slots

  const float* xT = x   + (size_t)(mt * BM) * K + s * KS;
  const float* wT = wgt + (size_t)(nt * BN) * K + s * KS;

  // --- fragment decode -------------------------------------------------
  const int wm = (wv & 1) * 64;        // wave M origin
  const int wn = (wv >> 1) * 64;       // wave N origin
  const int lr = lane & 15;
  const int lq = lane >> 4;
  const int q0 = (2 * lq) ^ (lr & 7);  // swizzled LDS chunk of this lane's frag

  f4 acc[4][4] = {};

  // stage tile 0 into buffer 0
#pragma unroll
  for (int j = 0; j < 4; ++j) {
    async16(xT + goff[j], &As[0][lbase + j * 256]);
    async16(wT + goff[j], &Bs[0][lbase + j * 256]);
  }
  __syncthreads();   // drains vmcnt -> tile 0 visible

  for (int kk = 0; kk < NITER; ++kk) {
    const int cur = kk & 1;

    // async-stage tile kk+1 into the other buffer (completes by the barrier)
    if (kk + 1 < NITER) {
      const float* xn = xT + (kk + 1) * BK;
      const float* wn2 = wT + (kk + 1) * BK;
#pragma unroll
      for (int j = 0; j < 4; ++j) {
        async16(xn + goff[j],  &As[cur ^ 1][lbase + j * 256]);
        async16(wn2 + goff[j], &Bs[cur ^ 1][lbase + j * 256]);
      }
    }

    // fragments (fp32 in LDS -> bf16 in regs) + MFMA
    bf8 af[4], bfv[4];
#pragma unroll
    for (int mf = 0; mf < 4; ++mf)
      af[mf] = load_frag(&As[cur][(wm + mf * 16 + lr) * BK], q0);
#pragma unroll
    for (int nf = 0; nf < 4; ++nf)
      bfv[nf] = load_frag(&Bs[cur][(wn + nf * 16 + lr) * BK], q0);

#pragma unroll
    for (int mf = 0; mf < 4; ++mf)
#pragma unroll
      for (int nf = 0; nf < 4; ++nf)
        acc[mf][nf] = __builtin_amdgcn_mfma_f32_16x16x32_bf16(af[mf], bfv[nf], acc[mf][nf], 0, 0, 0);

    __syncthreads();   // waits compute readers AND drains next-tile DMA
  }

  // epilogue: write fp32 partial into column-copy s of d_out
  float* ob = out + (size_t)(mt * BM) * OUTF + s * NS + nt * BN;
#pragma unroll
  for (int mf = 0; mf < 4; ++mf) {
#pragma unroll
    for (int nf = 0; nf < 4; ++nf) {
#pragma unroll
      for (int r = 0; r < 4; ++r) {
        const int row = wm + mf * 16 + lq * 4 + r;
        const int col = wn + nf * 16 + lr;
        ob[(size_t)row * OUTF + col] = acc[mf][nf][r];
      }
    }
  }
}

// Sum the 4 K-split partials (column copies 0..3), add bias, write all 8 copies.
__global__ __launch_bounds__(256)
void combine_kernel(float* __restrict__ out, const float* __restrict__ bias) {
  const int t = blockIdx.x * 256 + threadIdx.x;   // 524288 threads
  const int b  = t >> 7;                          // row 0..4095
  const int rc = t & 127;                         // float4 index within 512-col copy
  float4* row = reinterpret_cast<float4*>(out) + (size_t)b * (OUTF / 4);
  const float4* bias4 = reinterpret_cast<const float4*>(bias);

  float4 p[SK];
#pragma unroll
  for (int s2 = 0; s2 < SK; ++s2) p[s2] = row[s2 * 128 + rc];

  float sx = 0.f, sy = 0.f, sz = 0.f, sw = 0.f;
#pragma unroll
  for (int s2 = 0; s2 < SK; ++s2) {
    sx += p[s2].x; sy += p[s2].y; sz += p[s2].z; sw += p[s2].w;
  }

#pragma unroll
  for (int c = 0; c < 8; ++c) {
    float4 bb = bias4[c * 128 + rc];
    float4 o;
    o.x = sx + bb.x; o.y = sy + bb.y; o.z = sz + bb.z; o.w = sw + bb.w;
    row[c * 128 + rc] = o;
  }
}

extern "C" void kernel_launch(void* const* d_in, const int* in_sizes, int n_in,
                              void* d_out, int out_size, void* d_ws, size_t ws_size,
                              hipStream_t stream) {
  (void)in_sizes; (void)n_in; (void)d_ws; (void)ws_size; (void)out_size;
  const float* x    = (const float*)d_in[0];
  const float* wgt  = (const float*)d_in[1];
  const float* bias = (const float*)d_in[2];
  float* out = (float*)d_out;

  gemm_split_kernel<<<dim3(32 * 4 * SK), dim3(256), 0, stream>>>(x, wgt, out);
  combine_kernel<<<dim3((M * NS / 4) / 256), dim3(256), 0, stream>>>(out, bias);
}